// Round 17
// baseline (65.920 us; speedup 1.0000x reference)
//
#include <hip/hip_runtime.h>

typedef _Float16 f16;
typedef _Float16 f16x4 __attribute__((ext_vector_type(4)));
typedef _Float16 n16x2 __attribute__((ext_vector_type(2)));
typedef float    f32x4 __attribute__((ext_vector_type(4)));

#define LOG2E 1.44269504088896340736f
#define OFF25 36.0673760222824936f   /* 25 * log2(e) */

__device__ __forceinline__ f32x4 MFMA(f16x4 a, f16x4 b, f32x4 c) {
#if defined(__HIP_DEVICE_COMPILE__)
    return __builtin_amdgcn_mfma_f32_16x16x16f16(a, b, c, 0, 0, 0);
#else
    return c;   // host parse stub — never executed
#endif
}

__device__ __forceinline__ float fexp2(float x) {
#if defined(__HIP_DEVICE_COMPILE__)
    return __builtin_amdgcn_exp2f(x);
#else
    return exp2f(x);
#endif
}

__device__ __forceinline__ float flog2(float x) {
#if defined(__HIP_DEVICE_COMPILE__)
    return __builtin_amdgcn_logf(x);     // v_log_f32 = log2
#else
    return log2f(x);
#endif
}

__device__ __forceinline__ f16x4 pk4(float a, float b, float c, float d) {
#if defined(__HIP_DEVICE_COMPILE__)
    n16x2 lo = __builtin_bit_cast(n16x2, __builtin_amdgcn_cvt_pkrtz(a, b));
    n16x2 hi = __builtin_bit_cast(n16x2, __builtin_amdgcn_cvt_pkrtz(c, d));
    f16x4 r; r[0] = lo[0]; r[1] = lo[1]; r[2] = hi[0]; r[3] = hi[1];
    return r;
#else
    f16x4 r; r[0] = (f16)a; r[1] = (f16)b; r[2] = (f16)c; r[3] = (f16)d;
    return r;
#endif
}

// ---------------------------------------------------------------------------
// K1: projections, K-split (unchanged from round 16).
// ---------------------------------------------------------------------------
__global__ __launch_bounds__(256) void k_proj(const float* __restrict__ x,
        const float* __restrict__ wf, const float* __restrict__ wg,
        const float* __restrict__ wh, f16* __restrict__ F,
        f16* __restrict__ G, f16* __restrict__ Hf) {
    const int lane = threadIdx.x & 63;
    const int wid  = threadIdx.x >> 6;
    const int tile = wid >> 1;
    const int kh   = wid & 1;
    const int g16  = lane >> 4;
    const int c16  = lane & 15;
    const long r0  = ((long)blockIdx.x * 2 + tile) * 16;

    f16x4 bw[3][4];
    const float* Ws[3] = { wf, wg, wh };
    #pragma unroll
    for (int w = 0; w < 3; ++w)
        #pragma unroll
        for (int kk = 0; kk < 4; ++kk) {
            const int kb = (kh * 4 + kk) * 16 + g16 * 4;
            bw[w][kk] = pk4(Ws[w][(kb + 0) * 16 + c16], Ws[w][(kb + 1) * 16 + c16],
                            Ws[w][(kb + 2) * 16 + c16], Ws[w][(kb + 3) * 16 + c16]);
        }

    f32x4 af = {0,0,0,0}, ag = {0,0,0,0}, ah = {0,0,0,0};
    const float* xr = x + (r0 + c16) * 128;
    #pragma unroll
    for (int kk = 0; kk < 4; ++kk) {
        float4 xa = *(const float4*)(xr + (kh * 4 + kk) * 16 + g16 * 4);
        f16x4 a = pk4(xa.x, xa.y, xa.z, xa.w);
        af = MFMA(a, bw[0][kk], af);
        ag = MFMA(a, bw[1][kk], ag);
        ah = MFMA(a, bw[2][kk], ah);
    }

    __shared__ float red[2][64][13];
    if (kh == 1) {
        #pragma unroll
        for (int i = 0; i < 4; ++i) {
            red[tile][lane][i]     = af[i];
            red[tile][lane][4 + i] = ag[i];
            red[tile][lane][8 + i] = ah[i];
        }
    }
    __syncthreads();
    if (kh == 0) {
        #pragma unroll
        for (int i = 0; i < 4; ++i) {
            af[i] += red[tile][lane][i];
            ag[i] += red[tile][lane][4 + i];
            ah[i] += red[tile][lane][8 + i];
        }
        #pragma unroll
        for (int i = 0; i < 4; ++i) {
            const long row = r0 + g16 * 4 + i;
            F[row * 16 + c16] = (f16)(af[i] * LOG2E);   // exp2-domain F
            G[row * 16 + c16] = (f16)ag[i];
        }
        *(f16x4*)(Hf + (r0 >> 4) * 256 + lane * 4) =
            pk4(ah[0], ah[1], ah[2], ah[3]);
    }
}

// ---------------------------------------------------------------------------
// K2: column Z, XCD swizzle, DUAL n-stream ILP.  Block = 64 m (ga[4]/wave);
// wave tp covers 512 n as 16 iters x 2 n-tiles (8 indep MFMA+exp chains).
// ---------------------------------------------------------------------------
__global__ __launch_bounds__(512) void k_cs(const f16* __restrict__ F,
        const f16* __restrict__ G, float* __restrict__ nM2) {
    const int lane = threadIdx.x & 63;
    const int tp   = threadIdx.x >> 6;               // 0..7 n-partition
    const int b    = blockIdx.x & 7;                 // XCD swizzle: batch
    const int mb   = (blockIdx.x >> 3) * 64;         //              m-block
    const int g16  = lane >> 4, c16 = lane & 15;
    const long bb  = (long)b * 4096;

    f16x4 ga[4];
    #pragma unroll
    for (int j = 0; j < 4; ++j)
        ga[j] = *(const f16x4*)(G + (bb + mb + 16 * j + c16) * 16 + g16 * 4);

    const f16* Fb = F + (bb + tp * 512) * 16;
    float zsa[4][4], zsb[4][4];
    #pragma unroll
    for (int j = 0; j < 4; ++j)
        #pragma unroll
        for (int i = 0; i < 4; ++i) { zsa[j][i] = 0.f; zsb[j][i] = 0.f; }

    const f32x4 coff = {-OFF25, -OFF25, -OFF25, -OFF25};
    f16x4 fa0 = *(const f16x4*)(Fb + (0 * 16 + c16) * 16 + g16 * 4);
    f16x4 fb0 = *(const f16x4*)(Fb + (1 * 16 + c16) * 16 + g16 * 4);
    f16x4 fa1 = *(const f16x4*)(Fb + (2 * 16 + c16) * 16 + g16 * 4);
    f16x4 fb1 = *(const f16x4*)(Fb + (3 * 16 + c16) * 16 + g16 * 4);
    for (int t = 0; t < 16; ++t) {
        // pair-prefetch (PAD covers tail over-read)
        f16x4 fa2 = *(const f16x4*)(Fb + ((2 * t + 4) * 16 + c16) * 16 + g16 * 4);
        f16x4 fb2 = *(const f16x4*)(Fb + ((2 * t + 5) * 16 + c16) * 16 + g16 * 4);
        #pragma unroll
        for (int j = 0; j < 4; ++j) {
            f32x4 sa = MFMA(ga[j], fa0, coff);
            f32x4 sb = MFMA(ga[j], fb0, coff);
            #pragma unroll
            for (int i = 0; i < 4; ++i) {
                zsa[j][i] += fexp2(sa[i]);
                zsb[j][i] += fexp2(sb[i]);
            }
        }
        fa0 = fa1; fb0 = fb1; fa1 = fa2; fb1 = fb2;
    }
    float zs[4][4];
    #pragma unroll
    for (int j = 0; j < 4; ++j)
        #pragma unroll
        for (int i = 0; i < 4; ++i) zs[j][i] = zsa[j][i] + zsb[j][i];
    #pragma unroll
    for (int d = 8; d >= 1; d >>= 1)
        #pragma unroll
        for (int j = 0; j < 4; ++j)
            #pragma unroll
            for (int i = 0; i < 4; ++i)
                zs[j][i] += __shfl_xor(zs[j][i], d);

    __shared__ float lz[8][64];
    if (c16 == 0) {
        #pragma unroll
        for (int j = 0; j < 4; ++j)
            #pragma unroll
            for (int i = 0; i < 4; ++i)
                lz[tp][16 * j + 4 * g16 + i] = zs[j][i];
    }
    __syncthreads();
    if (threadIdx.x < 64) {
        const int ml = threadIdx.x;
        float z = 0.f;
        #pragma unroll
        for (int p = 0; p < 8; ++p) z += lz[p][ml];
        nM2[bb + mb + ml] = -flog2(z) - OFF25;
    }
}

// ---------------------------------------------------------------------------
// K3: PV + fused output projection, XCD swizzle, DUAL m-stream ILP.
// Block = 64 n (fbv[4]); wave tp covers 512 m as 16 iters x 2 m-tiles.
// Separate yTa/yTb accumulators keep all 8 MFMA chains independent.
// ---------------------------------------------------------------------------
__global__ __launch_bounds__(512) void k_pv(const f16* __restrict__ F,
        const f16* __restrict__ G, const f16* __restrict__ Hf,
        const float* __restrict__ nM2, const float* __restrict__ wv,
        const float* __restrict__ xin, const float* __restrict__ gamma,
        float* __restrict__ out) {
    const int lane = threadIdx.x & 63;
    const int tp   = threadIdx.x >> 6;               // 0..7 m-partition
    const int b    = blockIdx.x & 7;                 // XCD swizzle: batch
    const int n0   = (blockIdx.x >> 3) * 64;         //              n-block
    const int g16  = lane >> 4, c16 = lane & 15;
    const long bb  = (long)b * 4096;

    f16x4 fbv[4];
    #pragma unroll
    for (int j = 0; j < 4; ++j)
        fbv[j] = *(const f16x4*)(F + (bb + n0 + 16 * j + c16) * 16 + g16 * 4);

    // epilogue assignment: wave tp -> n-tile jo, col-half th
    const int jo = tp >> 1, th = tp & 1;
    const float gm = gamma[0];
    f16x4 wvf[4];
    #pragma unroll
    for (int t = 0; t < 4; ++t) {
        const int c0 = (4 * th + t) * 16;
        wvf[t] = pk4(wv[(g16 * 4 + 0) * 128 + c0 + c16] * gm,
                     wv[(g16 * 4 + 1) * 128 + c0 + c16] * gm,
                     wv[(g16 * 4 + 2) * 128 + c0 + c16] * gm,
                     wv[(g16 * 4 + 3) * 128 + c0 + c16] * gm);
    }

    const f16* Gp = G + bb * 16;
    const f16* Hp = Hf + bb * 16 + lane * 4;         // frag-order: +m*16
    const float* Np = nM2 + bb;
    const int mbase = tp * 512;

    f32x4 yTa[4] = {{0,0,0,0},{0,0,0,0},{0,0,0,0},{0,0,0,0}};
    f32x4 yTb[4] = {{0,0,0,0},{0,0,0,0},{0,0,0,0},{0,0,0,0}};
    // pair streams: set0 = m-tiles {mbase, mbase+16}, set1 = {+32, +48}
    f16x4 gaa0 = *(const f16x4*)(Gp + (mbase + c16) * 16 + g16 * 4);
    f16x4 haa0 = *(const f16x4*)(Hp + (long)mbase * 16);
    f32x4 nma0 = *(const f32x4*)(Np + mbase + g16 * 4);
    f16x4 gab0 = *(const f16x4*)(Gp + (mbase + 16 + c16) * 16 + g16 * 4);
    f16x4 hab0 = *(const f16x4*)(Hp + (long)(mbase + 16) * 16);
    f32x4 nmb0 = *(const f32x4*)(Np + mbase + 16 + g16 * 4);
    f16x4 gaa1 = *(const f16x4*)(Gp + (mbase + 32 + c16) * 16 + g16 * 4);
    f16x4 haa1 = *(const f16x4*)(Hp + (long)(mbase + 32) * 16);
    f32x4 nma1 = *(const f32x4*)(Np + mbase + 32 + g16 * 4);
    f16x4 gab1 = *(const f16x4*)(Gp + (mbase + 48 + c16) * 16 + g16 * 4);
    f16x4 hab1 = *(const f16x4*)(Hp + (long)(mbase + 48) * 16);
    f32x4 nmb1 = *(const f32x4*)(Np + mbase + 48 + g16 * 4);
    for (int t = 0; t < 16; ++t) {
        const int mp = mbase + t * 32 + 64;   // pair-prefetch; PAD covers tail
        f16x4 gaa2 = *(const f16x4*)(Gp + (mp + c16) * 16 + g16 * 4);
        f16x4 haa2 = *(const f16x4*)(Hp + (long)mp * 16);
        f32x4 nma2 = *(const f32x4*)(Np + mp + g16 * 4);
        f16x4 gab2 = *(const f16x4*)(Gp + (mp + 16 + c16) * 16 + g16 * 4);
        f16x4 hab2 = *(const f16x4*)(Hp + (long)(mp + 16) * 16);
        f32x4 nmb2 = *(const f32x4*)(Np + mp + 16 + g16 * 4);
        #pragma unroll
        for (int j = 0; j < 4; ++j) {
            f32x4 sa = MFMA(gaa0, fbv[j], nma0);
            f16x4 pa = pk4(fexp2(sa[0]), fexp2(sa[1]),
                           fexp2(sa[2]), fexp2(sa[3]));
            yTa[j] = MFMA(haa0, pa, yTa[j]);
            f32x4 sb = MFMA(gab0, fbv[j], nmb0);
            f16x4 pb = pk4(fexp2(sb[0]), fexp2(sb[1]),
                           fexp2(sb[2]), fexp2(sb[3]));
            yTb[j] = MFMA(hab0, pb, yTb[j]);
        }
        gaa0 = gaa1; haa0 = haa1; nma0 = nma1;
        gab0 = gab1; hab0 = hab1; nmb0 = nmb1;
        gaa1 = gaa2; haa1 = haa2; nma1 = nma2;
        gab1 = gab2; hab1 = hab2; nmb1 = nmb2;
    }

    // cross-wave reduce: 8 m-partials per n-tile
    __shared__ float red[8][4][64][5];        // 40 KB, stride-5: conflict-free
    #pragma unroll
    for (int j = 0; j < 4; ++j)
        #pragma unroll
        for (int i = 0; i < 4; ++i) red[tp][j][lane][i] = yTa[j][i] + yTb[j][i];
    __syncthreads();

    f32x4 ys = {0,0,0,0};
    #pragma unroll
    for (int p = 0; p < 8; ++p)
        #pragma unroll
        for (int i = 0; i < 4; ++i) ys[i] += red[p][jo][lane][i];
    const f16x4 ya = pk4(ys[0], ys[1], ys[2], ys[3]);   // Y A-frag, n-tile jo

    #pragma unroll
    for (int t = 0; t < 4; ++t) {
        const int c0 = (4 * th + t) * 16;
        f32x4 zero = {0,0,0,0};
        f32x4 o = MFMA(ya, wvf[t], zero);
        #pragma unroll
        for (int i = 0; i < 4; ++i) {
            const long idx = (bb + n0 + 16 * jo + 4 * g16 + i) * 128 + c0 + c16;
            out[idx] = o[i] + xin[idx];
        }
    }
}

// ---------------------------------------------------------------------------
extern "C" void kernel_launch(void* const* d_in, const int* in_sizes, int n_in,
                              void* d_out, int out_size, void* d_ws, size_t ws_size,
                              hipStream_t stream) {
    const float* x     = (const float*)d_in[0];
    const float* wf    = (const float*)d_in[1];
    const float* wg    = (const float*)d_in[2];
    const float* wh    = (const float*)d_in[3];
    const float* wv    = (const float*)d_in[4];
    const float* gamma = (const float*)d_in[5];
    float* out = (float*)d_out;

    char* p = (char*)d_ws;
    const long BN  = 8L * 4096;
    const long PAD = 8192;
    f16*   F   = (f16*)p;    p += BN * 16 * sizeof(f16) + PAD;
    f16*   G   = (f16*)p;    p += BN * 16 * sizeof(f16) + PAD;
    f16*   Hf  = (f16*)p;    p += BN * 16 * sizeof(f16) + PAD;  // frag-order V
    float* nM2 = (float*)p;  p += BN * sizeof(float)    + PAD;

    k_proj<<<1024, 256, 0, stream>>>(x, wf, wg, wh, F, G, Hf);
    k_cs  <<<512,  512, 0, stream>>>(F, G, nM2);
    k_pv  <<<512,  512, 0, stream>>>(F, G, Hf, nM2, wv, x, gamma, out);
}

// Round 18
// 47.534 us; speedup vs baseline: 1.3868x; 1.3868x over previous
//
#include <hip/hip_runtime.h>

typedef _Float16 f16;
typedef _Float16 f16x4 __attribute__((ext_vector_type(4)));
typedef _Float16 n16x2 __attribute__((ext_vector_type(2)));
typedef float    f32x4 __attribute__((ext_vector_type(4)));

#define LOG2E 1.44269504088896340736f
#define OFF25 36.0673760222824936f   /* 25 * log2(e) */

__device__ __forceinline__ f32x4 MFMA(f16x4 a, f16x4 b, f32x4 c) {
#if defined(__HIP_DEVICE_COMPILE__)
    return __builtin_amdgcn_mfma_f32_16x16x16f16(a, b, c, 0, 0, 0);
#else
    return c;   // host parse stub — never executed
#endif
}

__device__ __forceinline__ float fexp2(float x) {
#if defined(__HIP_DEVICE_COMPILE__)
    return __builtin_amdgcn_exp2f(x);
#else
    return exp2f(x);
#endif
}

__device__ __forceinline__ float flog2(float x) {
#if defined(__HIP_DEVICE_COMPILE__)
    return __builtin_amdgcn_logf(x);     // v_log_f32 = log2
#else
    return log2f(x);
#endif
}

__device__ __forceinline__ f16x4 pk4(float a, float b, float c, float d) {
#if defined(__HIP_DEVICE_COMPILE__)
    n16x2 lo = __builtin_bit_cast(n16x2, __builtin_amdgcn_cvt_pkrtz(a, b));
    n16x2 hi = __builtin_bit_cast(n16x2, __builtin_amdgcn_cvt_pkrtz(c, d));
    f16x4 r; r[0] = lo[0]; r[1] = lo[1]; r[2] = hi[0]; r[3] = hi[1];
    return r;
#else
    f16x4 r; r[0] = (f16)a; r[1] = (f16)b; r[2] = (f16)c; r[3] = (f16)d;
    return r;
#endif
}

// ---------------------------------------------------------------------------
// K1: projections, K-split (unchanged from round 16).
// ---------------------------------------------------------------------------
__global__ __launch_bounds__(256) void k_proj(const float* __restrict__ x,
        const float* __restrict__ wf, const float* __restrict__ wg,
        const float* __restrict__ wh, f16* __restrict__ F,
        f16* __restrict__ G, f16* __restrict__ Hf) {
    const int lane = threadIdx.x & 63;
    const int wid  = threadIdx.x >> 6;
    const int tile = wid >> 1;
    const int kh   = wid & 1;
    const int g16  = lane >> 4;
    const int c16  = lane & 15;
    const long r0  = ((long)blockIdx.x * 2 + tile) * 16;

    f16x4 bw[3][4];
    const float* Ws[3] = { wf, wg, wh };
    #pragma unroll
    for (int w = 0; w < 3; ++w)
        #pragma unroll
        for (int kk = 0; kk < 4; ++kk) {
            const int kb = (kh * 4 + kk) * 16 + g16 * 4;
            bw[w][kk] = pk4(Ws[w][(kb + 0) * 16 + c16], Ws[w][(kb + 1) * 16 + c16],
                            Ws[w][(kb + 2) * 16 + c16], Ws[w][(kb + 3) * 16 + c16]);
        }

    f32x4 af = {0,0,0,0}, ag = {0,0,0,0}, ah = {0,0,0,0};
    const float* xr = x + (r0 + c16) * 128;
    #pragma unroll
    for (int kk = 0; kk < 4; ++kk) {
        float4 xa = *(const float4*)(xr + (kh * 4 + kk) * 16 + g16 * 4);
        f16x4 a = pk4(xa.x, xa.y, xa.z, xa.w);
        af = MFMA(a, bw[0][kk], af);
        ag = MFMA(a, bw[1][kk], ag);
        ah = MFMA(a, bw[2][kk], ah);
    }

    __shared__ float red[2][64][13];
    if (kh == 1) {
        #pragma unroll
        for (int i = 0; i < 4; ++i) {
            red[tile][lane][i]     = af[i];
            red[tile][lane][4 + i] = ag[i];
            red[tile][lane][8 + i] = ah[i];
        }
    }
    __syncthreads();
    if (kh == 0) {
        #pragma unroll
        for (int i = 0; i < 4; ++i) {
            af[i] += red[tile][lane][i];
            ag[i] += red[tile][lane][4 + i];
            ah[i] += red[tile][lane][8 + i];
        }
        #pragma unroll
        for (int i = 0; i < 4; ++i) {
            const long row = r0 + g16 * 4 + i;
            F[row * 16 + c16] = (f16)(af[i] * LOG2E);   // exp2-domain F
            G[row * 16 + c16] = (f16)ag[i];
        }
        *(f16x4*)(Hf + (r0 >> 4) * 256 + lane * 4) =
            pk4(ah[0], ah[1], ah[2], ah[3]);
    }
}

// ---------------------------------------------------------------------------
// K2: column Z, XCD swizzle, register-lean dual n-stream: 2 MFMA streams per
// iteration with SHARED accumulators (no zsa/zsb split -> no spill).
// ---------------------------------------------------------------------------
__global__ __launch_bounds__(512) void k_cs(const f16* __restrict__ F,
        const f16* __restrict__ G, float* __restrict__ nM2) {
    const int lane = threadIdx.x & 63;
    const int tp   = threadIdx.x >> 6;               // 0..7 n-partition
    const int b    = blockIdx.x & 7;                 // XCD swizzle: batch
    const int mb   = (blockIdx.x >> 3) * 64;         //              m-block
    const int g16  = lane >> 4, c16 = lane & 15;
    const long bb  = (long)b * 4096;

    f16x4 ga[4];
    #pragma unroll
    for (int j = 0; j < 4; ++j)
        ga[j] = *(const f16x4*)(G + (bb + mb + 16 * j + c16) * 16 + g16 * 4);

    const f16* Fb = F + (bb + tp * 512) * 16;
    float zs[4][4];
    #pragma unroll
    for (int j = 0; j < 4; ++j)
        #pragma unroll
        for (int i = 0; i < 4; ++i) zs[j][i] = 0.f;

    const f32x4 coff = {-OFF25, -OFF25, -OFF25, -OFF25};
    f16x4 fa0 = *(const f16x4*)(Fb + (0 * 16 + c16) * 16 + g16 * 4);
    f16x4 fb0 = *(const f16x4*)(Fb + (1 * 16 + c16) * 16 + g16 * 4);
    f16x4 fa1 = *(const f16x4*)(Fb + (2 * 16 + c16) * 16 + g16 * 4);
    f16x4 fb1 = *(const f16x4*)(Fb + (3 * 16 + c16) * 16 + g16 * 4);
    for (int t = 0; t < 16; ++t) {
        // pair-prefetch (PAD covers tail over-read)
        f16x4 fa2 = *(const f16x4*)(Fb + ((2 * t + 4) * 16 + c16) * 16 + g16 * 4);
        f16x4 fb2 = *(const f16x4*)(Fb + ((2 * t + 5) * 16 + c16) * 16 + g16 * 4);
        #pragma unroll
        for (int j = 0; j < 4; ++j) {
            f32x4 sa = MFMA(ga[j], fa0, coff);
            f32x4 sb = MFMA(ga[j], fb0, coff);
            #pragma unroll
            for (int i = 0; i < 4; ++i) {
                zs[j][i] += fexp2(sa[i]);
                zs[j][i] += fexp2(sb[i]);
            }
        }
        fa0 = fa1; fb0 = fb1; fa1 = fa2; fb1 = fb2;
    }
    #pragma unroll
    for (int d = 8; d >= 1; d >>= 1)
        #pragma unroll
        for (int j = 0; j < 4; ++j)
            #pragma unroll
            for (int i = 0; i < 4; ++i)
                zs[j][i] += __shfl_xor(zs[j][i], d);

    __shared__ float lz[8][64];
    if (c16 == 0) {
        #pragma unroll
        for (int j = 0; j < 4; ++j)
            #pragma unroll
            for (int i = 0; i < 4; ++i)
                lz[tp][16 * j + 4 * g16 + i] = zs[j][i];
    }
    __syncthreads();
    if (threadIdx.x < 64) {
        const int ml = threadIdx.x;
        float z = 0.f;
        #pragma unroll
        for (int p = 0; p < 8; ++p) z += lz[p][ml];
        nM2[bb + mb + ml] = -flog2(z) - OFF25;
    }
}

// ---------------------------------------------------------------------------
// K3: PV + fused output projection (round-16 exactly: single stream, T=4,
// depth-3 prefetch, XCD swizzle, linear Hf loads, nm via MFMA C-input).
// ---------------------------------------------------------------------------
__global__ __launch_bounds__(512) void k_pv(const f16* __restrict__ F,
        const f16* __restrict__ G, const f16* __restrict__ Hf,
        const float* __restrict__ nM2, const float* __restrict__ wv,
        const float* __restrict__ xin, const float* __restrict__ gamma,
        float* __restrict__ out) {
    const int lane = threadIdx.x & 63;
    const int tp   = threadIdx.x >> 6;               // 0..7 m-partition
    const int b    = blockIdx.x & 7;                 // XCD swizzle: batch
    const int n0   = (blockIdx.x >> 3) * 64;         //              n-block
    const int g16  = lane >> 4, c16 = lane & 15;
    const long bb  = (long)b * 4096;

    f16x4 fbv[4];
    #pragma unroll
    for (int j = 0; j < 4; ++j)
        fbv[j] = *(const f16x4*)(F + (bb + n0 + 16 * j + c16) * 16 + g16 * 4);

    // epilogue assignment: wave tp -> n-tile jo, col-half th
    const int jo = tp >> 1, th = tp & 1;
    const float gm = gamma[0];
    f16x4 wvf[4];
    #pragma unroll
    for (int t = 0; t < 4; ++t) {
        const int c0 = (4 * th + t) * 16;
        wvf[t] = pk4(wv[(g16 * 4 + 0) * 128 + c0 + c16] * gm,
                     wv[(g16 * 4 + 1) * 128 + c0 + c16] * gm,
                     wv[(g16 * 4 + 2) * 128 + c0 + c16] * gm,
                     wv[(g16 * 4 + 3) * 128 + c0 + c16] * gm);
    }

    const f16* Gp = G + bb * 16;
    const f16* Hp = Hf + bb * 16 + lane * 4;         // frag-order: +m*16
    const float* Np = nM2 + bb;
    const int mbase = tp * 512;

    f32x4 yT[4] = {{0,0,0,0},{0,0,0,0},{0,0,0,0},{0,0,0,0}};
    f16x4 ga0 = *(const f16x4*)(Gp + (mbase + c16) * 16 + g16 * 4);
    f16x4 ha0 = *(const f16x4*)(Hp + (long)mbase * 16);
    f32x4 nm0 = *(const f32x4*)(Np + mbase + g16 * 4);
    f16x4 ga1 = *(const f16x4*)(Gp + (mbase + 16 + c16) * 16 + g16 * 4);
    f16x4 ha1 = *(const f16x4*)(Hp + (long)(mbase + 16) * 16);
    f32x4 nm1 = *(const f32x4*)(Np + mbase + 16 + g16 * 4);
    f16x4 ga2 = *(const f16x4*)(Gp + (mbase + 32 + c16) * 16 + g16 * 4);
    f16x4 ha2 = *(const f16x4*)(Hp + (long)(mbase + 32) * 16);
    f32x4 nm2 = *(const f32x4*)(Np + mbase + 32 + g16 * 4);
    for (int t = 0; t < 32; ++t) {
        const int m3 = mbase + t * 16 + 48;   // depth-3; padded: over-read safe
        f16x4 gan = *(const f16x4*)(Gp + (m3 + c16) * 16 + g16 * 4);
        f16x4 han = *(const f16x4*)(Hp + (long)m3 * 16);
        f32x4 nmn = *(const f32x4*)(Np + m3 + g16 * 4);
        #pragma unroll
        for (int j = 0; j < 4; ++j) {
            f32x4 s = MFMA(ga0, fbv[j], nm0);        // q = s' + nm
            f16x4 pb = pk4(fexp2(s[0]), fexp2(s[1]),
                           fexp2(s[2]), fexp2(s[3]));
            yT[j] = MFMA(ha0, pb, yT[j]);
        }
        ga0 = ga1; ha0 = ha1; nm0 = nm1;
        ga1 = ga2; ha1 = ha2; nm1 = nm2;
        ga2 = gan; ha2 = han; nm2 = nmn;
    }

    // cross-wave reduce: 8 m-partials per n-tile
    __shared__ float red[8][4][64][5];        // 40 KB, stride-5: conflict-free
    #pragma unroll
    for (int j = 0; j < 4; ++j)
        #pragma unroll
        for (int i = 0; i < 4; ++i) red[tp][j][lane][i] = yT[j][i];
    __syncthreads();

    f32x4 ys = {0,0,0,0};
    #pragma unroll
    for (int p = 0; p < 8; ++p)
        #pragma unroll
        for (int i = 0; i < 4; ++i) ys[i] += red[p][jo][lane][i];
    const f16x4 ya = pk4(ys[0], ys[1], ys[2], ys[3]);   // Y A-frag, n-tile jo

    #pragma unroll
    for (int t = 0; t < 4; ++t) {
        const int c0 = (4 * th + t) * 16;
        f32x4 zero = {0,0,0,0};
        f32x4 o = MFMA(ya, wvf[t], zero);
        #pragma unroll
        for (int i = 0; i < 4; ++i) {
            const long idx = (bb + n0 + 16 * jo + 4 * g16 + i) * 128 + c0 + c16;
            out[idx] = o[i] + xin[idx];
        }
    }
}

// ---------------------------------------------------------------------------
extern "C" void kernel_launch(void* const* d_in, const int* in_sizes, int n_in,
                              void* d_out, int out_size, void* d_ws, size_t ws_size,
                              hipStream_t stream) {
    const float* x     = (const float*)d_in[0];
    const float* wf    = (const float*)d_in[1];
    const float* wg    = (const float*)d_in[2];
    const float* wh    = (const float*)d_in[3];
    const float* wv    = (const float*)d_in[4];
    const float* gamma = (const float*)d_in[5];
    float* out = (float*)d_out;

    char* p = (char*)d_ws;
    const long BN  = 8L * 4096;
    const long PAD = 8192;
    f16*   F   = (f16*)p;    p += BN * 16 * sizeof(f16) + PAD;
    f16*   G   = (f16*)p;    p += BN * 16 * sizeof(f16) + PAD;
    f16*   Hf  = (f16*)p;    p += BN * 16 * sizeof(f16) + PAD;  // frag-order V
    float* nM2 = (float*)p;  p += BN * sizeof(float)    + PAD;

    k_proj<<<1024, 256, 0, stream>>>(x, wf, wg, wh, F, G, Hf);
    k_cs  <<<512,  512, 0, stream>>>(F, G, nM2);
    k_pv  <<<512,  512, 0, stream>>>(F, G, Hf, nM2, wv, x, gamma, out);
}

// Round 19
// 46.827 us; speedup vs baseline: 1.4077x; 1.0151x over previous
//
#include <hip/hip_runtime.h>

typedef _Float16 f16;
typedef _Float16 f16x4 __attribute__((ext_vector_type(4)));
typedef _Float16 n16x2 __attribute__((ext_vector_type(2)));
typedef float    f32x4 __attribute__((ext_vector_type(4)));

#define LOG2E 1.44269504088896340736f
#define OFF25 36.0673760222824936f   /* 25 * log2(e) */

__device__ __forceinline__ f32x4 MFMA(f16x4 a, f16x4 b, f32x4 c) {
#if defined(__HIP_DEVICE_COMPILE__)
    return __builtin_amdgcn_mfma_f32_16x16x16f16(a, b, c, 0, 0, 0);
#else
    return c;   // host parse stub — never executed
#endif
}

__device__ __forceinline__ float fexp2(float x) {
#if defined(__HIP_DEVICE_COMPILE__)
    return __builtin_amdgcn_exp2f(x);
#else
    return exp2f(x);
#endif
}

__device__ __forceinline__ float flog2(float x) {
#if defined(__HIP_DEVICE_COMPILE__)
    return __builtin_amdgcn_logf(x);     // v_log_f32 = log2
#else
    return log2f(x);
#endif
}

__device__ __forceinline__ f16x4 pk4(float a, float b, float c, float d) {
#if defined(__HIP_DEVICE_COMPILE__)
    n16x2 lo = __builtin_bit_cast(n16x2, __builtin_amdgcn_cvt_pkrtz(a, b));
    n16x2 hi = __builtin_bit_cast(n16x2, __builtin_amdgcn_cvt_pkrtz(c, d));
    f16x4 r; r[0] = lo[0]; r[1] = lo[1]; r[2] = hi[0]; r[3] = hi[1];
    return r;
#else
    f16x4 r; r[0] = (f16)a; r[1] = (f16)b; r[2] = (f16)c; r[3] = (f16)d;
    return r;
#endif
}

// ---------------------------------------------------------------------------
// K1: projections, K-split (unchanged from round 16).
// ---------------------------------------------------------------------------
__global__ __launch_bounds__(256) void k_proj(const float* __restrict__ x,
        const float* __restrict__ wf, const float* __restrict__ wg,
        const float* __restrict__ wh, f16* __restrict__ F,
        f16* __restrict__ G, f16* __restrict__ Hf) {
    const int lane = threadIdx.x & 63;
    const int wid  = threadIdx.x >> 6;
    const int tile = wid >> 1;
    const int kh   = wid & 1;
    const int g16  = lane >> 4;
    const int c16  = lane & 15;
    const long r0  = ((long)blockIdx.x * 2 + tile) * 16;

    f16x4 bw[3][4];
    const float* Ws[3] = { wf, wg, wh };
    #pragma unroll
    for (int w = 0; w < 3; ++w)
        #pragma unroll
        for (int kk = 0; kk < 4; ++kk) {
            const int kb = (kh * 4 + kk) * 16 + g16 * 4;
            bw[w][kk] = pk4(Ws[w][(kb + 0) * 16 + c16], Ws[w][(kb + 1) * 16 + c16],
                            Ws[w][(kb + 2) * 16 + c16], Ws[w][(kb + 3) * 16 + c16]);
        }

    f32x4 af = {0,0,0,0}, ag = {0,0,0,0}, ah = {0,0,0,0};
    const float* xr = x + (r0 + c16) * 128;
    #pragma unroll
    for (int kk = 0; kk < 4; ++kk) {
        float4 xa = *(const float4*)(xr + (kh * 4 + kk) * 16 + g16 * 4);
        f16x4 a = pk4(xa.x, xa.y, xa.z, xa.w);
        af = MFMA(a, bw[0][kk], af);
        ag = MFMA(a, bw[1][kk], ag);
        ah = MFMA(a, bw[2][kk], ah);
    }

    __shared__ float red[2][64][13];
    if (kh == 1) {
        #pragma unroll
        for (int i = 0; i < 4; ++i) {
            red[tile][lane][i]     = af[i];
            red[tile][lane][4 + i] = ag[i];
            red[tile][lane][8 + i] = ah[i];
        }
    }
    __syncthreads();
    if (kh == 0) {
        #pragma unroll
        for (int i = 0; i < 4; ++i) {
            af[i] += red[tile][lane][i];
            ag[i] += red[tile][lane][4 + i];
            ah[i] += red[tile][lane][8 + i];
        }
        #pragma unroll
        for (int i = 0; i < 4; ++i) {
            const long row = r0 + g16 * 4 + i;
            F[row * 16 + c16] = (f16)(af[i] * LOG2E);   // exp2-domain F
            G[row * 16 + c16] = (f16)ag[i];
        }
        *(f16x4*)(Hf + (r0 >> 4) * 256 + lane * 4) =
            pk4(ah[0], ah[1], ah[2], ah[3]);
    }
}

// ---------------------------------------------------------------------------
// K2: column Z, XCD swizzle, register-lean dual n-stream (round-18, proven).
// ---------------------------------------------------------------------------
__global__ __launch_bounds__(512) void k_cs(const f16* __restrict__ F,
        const f16* __restrict__ G, float* __restrict__ nM2) {
    const int lane = threadIdx.x & 63;
    const int tp   = threadIdx.x >> 6;               // 0..7 n-partition
    const int b    = blockIdx.x & 7;                 // XCD swizzle: batch
    const int mb   = (blockIdx.x >> 3) * 64;         //              m-block
    const int g16  = lane >> 4, c16 = lane & 15;
    const long bb  = (long)b * 4096;

    f16x4 ga[4];
    #pragma unroll
    for (int j = 0; j < 4; ++j)
        ga[j] = *(const f16x4*)(G + (bb + mb + 16 * j + c16) * 16 + g16 * 4);

    const f16* Fb = F + (bb + tp * 512) * 16;
    float zs[4][4];
    #pragma unroll
    for (int j = 0; j < 4; ++j)
        #pragma unroll
        for (int i = 0; i < 4; ++i) zs[j][i] = 0.f;

    const f32x4 coff = {-OFF25, -OFF25, -OFF25, -OFF25};
    f16x4 fa0 = *(const f16x4*)(Fb + (0 * 16 + c16) * 16 + g16 * 4);
    f16x4 fb0 = *(const f16x4*)(Fb + (1 * 16 + c16) * 16 + g16 * 4);
    f16x4 fa1 = *(const f16x4*)(Fb + (2 * 16 + c16) * 16 + g16 * 4);
    f16x4 fb1 = *(const f16x4*)(Fb + (3 * 16 + c16) * 16 + g16 * 4);
    for (int t = 0; t < 16; ++t) {
        f16x4 fa2 = *(const f16x4*)(Fb + ((2 * t + 4) * 16 + c16) * 16 + g16 * 4);
        f16x4 fb2 = *(const f16x4*)(Fb + ((2 * t + 5) * 16 + c16) * 16 + g16 * 4);
        #pragma unroll
        for (int j = 0; j < 4; ++j) {
            f32x4 sa = MFMA(ga[j], fa0, coff);
            f32x4 sb = MFMA(ga[j], fb0, coff);
            #pragma unroll
            for (int i = 0; i < 4; ++i) {
                zs[j][i] += fexp2(sa[i]);
                zs[j][i] += fexp2(sb[i]);
            }
        }
        fa0 = fa1; fb0 = fb1; fa1 = fa2; fb1 = fb2;
    }
    #pragma unroll
    for (int d = 8; d >= 1; d >>= 1)
        #pragma unroll
        for (int j = 0; j < 4; ++j)
            #pragma unroll
            for (int i = 0; i < 4; ++i)
                zs[j][i] += __shfl_xor(zs[j][i], d);

    __shared__ float lz[8][64];
    if (c16 == 0) {
        #pragma unroll
        for (int j = 0; j < 4; ++j)
            #pragma unroll
            for (int i = 0; i < 4; ++i)
                lz[tp][16 * j + 4 * g16 + i] = zs[j][i];
    }
    __syncthreads();
    if (threadIdx.x < 64) {
        const int ml = threadIdx.x;
        float z = 0.f;
        #pragma unroll
        for (int p = 0; p < 8; ++p) z += lz[p][ml];
        nM2[bb + mb + ml] = -flog2(z) - OFF25;
    }
}

// ---------------------------------------------------------------------------
// K3: PV + fused output projection, XCD swizzle, DUAL m-stream ILP (round-17
// version — inferred ~15us, masked then by k_cs spill).  Separate yTa/yTb
// accumulators keep all 8 MFMA chains independent; 16 iters x 2 m-tiles.
// ---------------------------------------------------------------------------
__global__ __launch_bounds__(512) void k_pv(const f16* __restrict__ F,
        const f16* __restrict__ G, const f16* __restrict__ Hf,
        const float* __restrict__ nM2, const float* __restrict__ wv,
        const float* __restrict__ xin, const float* __restrict__ gamma,
        float* __restrict__ out) {
    const int lane = threadIdx.x & 63;
    const int tp   = threadIdx.x >> 6;               // 0..7 m-partition
    const int b    = blockIdx.x & 7;                 // XCD swizzle: batch
    const int n0   = (blockIdx.x >> 3) * 64;         //              n-block
    const int g16  = lane >> 4, c16 = lane & 15;
    const long bb  = (long)b * 4096;

    f16x4 fbv[4];
    #pragma unroll
    for (int j = 0; j < 4; ++j)
        fbv[j] = *(const f16x4*)(F + (bb + n0 + 16 * j + c16) * 16 + g16 * 4);

    // epilogue assignment: wave tp -> n-tile jo, col-half th
    const int jo = tp >> 1, th = tp & 1;
    const float gm = gamma[0];
    f16x4 wvf[4];
    #pragma unroll
    for (int t = 0; t < 4; ++t) {
        const int c0 = (4 * th + t) * 16;
        wvf[t] = pk4(wv[(g16 * 4 + 0) * 128 + c0 + c16] * gm,
                     wv[(g16 * 4 + 1) * 128 + c0 + c16] * gm,
                     wv[(g16 * 4 + 2) * 128 + c0 + c16] * gm,
                     wv[(g16 * 4 + 3) * 128 + c0 + c16] * gm);
    }

    const f16* Gp = G + bb * 16;
    const f16* Hp = Hf + bb * 16 + lane * 4;         // frag-order: +m*16
    const float* Np = nM2 + bb;
    const int mbase = tp * 512;

    f32x4 yTa[4] = {{0,0,0,0},{0,0,0,0},{0,0,0,0},{0,0,0,0}};
    f32x4 yTb[4] = {{0,0,0,0},{0,0,0,0},{0,0,0,0},{0,0,0,0}};
    // pair streams: set0 = m-tiles {mbase, mbase+16}, set1 = {+32, +48}
    f16x4 gaa0 = *(const f16x4*)(Gp + (mbase + c16) * 16 + g16 * 4);
    f16x4 haa0 = *(const f16x4*)(Hp + (long)mbase * 16);
    f32x4 nma0 = *(const f32x4*)(Np + mbase + g16 * 4);
    f16x4 gab0 = *(const f16x4*)(Gp + (mbase + 16 + c16) * 16 + g16 * 4);
    f16x4 hab0 = *(const f16x4*)(Hp + (long)(mbase + 16) * 16);
    f32x4 nmb0 = *(const f32x4*)(Np + mbase + 16 + g16 * 4);
    f16x4 gaa1 = *(const f16x4*)(Gp + (mbase + 32 + c16) * 16 + g16 * 4);
    f16x4 haa1 = *(const f16x4*)(Hp + (long)(mbase + 32) * 16);
    f32x4 nma1 = *(const f32x4*)(Np + mbase + 32 + g16 * 4);
    f16x4 gab1 = *(const f16x4*)(Gp + (mbase + 48 + c16) * 16 + g16 * 4);
    f16x4 hab1 = *(const f16x4*)(Hp + (long)(mbase + 48) * 16);
    f32x4 nmb1 = *(const f32x4*)(Np + mbase + 48 + g16 * 4);
    for (int t = 0; t < 16; ++t) {
        const int mp = mbase + t * 32 + 64;   // pair-prefetch; PAD covers tail
        f16x4 gaa2 = *(const f16x4*)(Gp + (mp + c16) * 16 + g16 * 4);
        f16x4 haa2 = *(const f16x4*)(Hp + (long)mp * 16);
        f32x4 nma2 = *(const f32x4*)(Np + mp + g16 * 4);
        f16x4 gab2 = *(const f16x4*)(Gp + (mp + 16 + c16) * 16 + g16 * 4);
        f16x4 hab2 = *(const f16x4*)(Hp + (long)(mp + 16) * 16);
        f32x4 nmb2 = *(const f32x4*)(Np + mp + 16 + g16 * 4);
        #pragma unroll
        for (int j = 0; j < 4; ++j) {
            f32x4 sa = MFMA(gaa0, fbv[j], nma0);
            f16x4 pa = pk4(fexp2(sa[0]), fexp2(sa[1]),
                           fexp2(sa[2]), fexp2(sa[3]));
            yTa[j] = MFMA(haa0, pa, yTa[j]);
            f32x4 sb = MFMA(gab0, fbv[j], nmb0);
            f16x4 pb = pk4(fexp2(sb[0]), fexp2(sb[1]),
                           fexp2(sb[2]), fexp2(sb[3]));
            yTb[j] = MFMA(hab0, pb, yTb[j]);
        }
        gaa0 = gaa1; haa0 = haa1; nma0 = nma1;
        gab0 = gab1; hab0 = hab1; nmb0 = nmb1;
        gaa1 = gaa2; haa1 = haa2; nma1 = nma2;
        gab1 = gab2; hab1 = hab2; nmb1 = nmb2;
    }

    // cross-wave reduce: 8 m-partials per n-tile
    __shared__ float red[8][4][64][5];        // 40 KB, stride-5: conflict-free
    #pragma unroll
    for (int j = 0; j < 4; ++j)
        #pragma unroll
        for (int i = 0; i < 4; ++i) red[tp][j][lane][i] = yTa[j][i] + yTb[j][i];
    __syncthreads();

    f32x4 ys = {0,0,0,0};
    #pragma unroll
    for (int p = 0; p < 8; ++p)
        #pragma unroll
        for (int i = 0; i < 4; ++i) ys[i] += red[p][jo][lane][i];
    const f16x4 ya = pk4(ys[0], ys[1], ys[2], ys[3]);   // Y A-frag, n-tile jo

    #pragma unroll
    for (int t = 0; t < 4; ++t) {
        const int c0 = (4 * th + t) * 16;
        f32x4 zero = {0,0,0,0};
        f32x4 o = MFMA(ya, wvf[t], zero);
        #pragma unroll
        for (int i = 0; i < 4; ++i) {
            const long idx = (bb + n0 + 16 * jo + 4 * g16 + i) * 128 + c0 + c16;
            out[idx] = o[i] + xin[idx];
        }
    }
}

// ---------------------------------------------------------------------------
extern "C" void kernel_launch(void* const* d_in, const int* in_sizes, int n_in,
                              void* d_out, int out_size, void* d_ws, size_t ws_size,
                              hipStream_t stream) {
    const float* x     = (const float*)d_in[0];
    const float* wf    = (const float*)d_in[1];
    const float* wg    = (const float*)d_in[2];
    const float* wh    = (const float*)d_in[3];
    const float* wv    = (const float*)d_in[4];
    const float* gamma = (const float*)d_in[5];
    float* out = (float*)d_out;

    char* p = (char*)d_ws;
    const long BN  = 8L * 4096;
    const long PAD = 8192;
    f16*   F   = (f16*)p;    p += BN * 16 * sizeof(f16) + PAD;
    f16*   G   = (f16*)p;    p += BN * 16 * sizeof(f16) + PAD;
    f16*   Hf  = (f16*)p;    p += BN * 16 * sizeof(f16) + PAD;  // frag-order V
    float* nM2 = (float*)p;  p += BN * sizeof(float)    + PAD;

    k_proj<<<1024, 256, 0, stream>>>(x, wf, wg, wh, F, G, Hf);
    k_cs  <<<512,  512, 0, stream>>>(F, G, nM2);
    k_pv  <<<512,  512, 0, stream>>>(F, G, Hf, nM2, wv, x, gamma, out);
}

// Round 20
// 46.180 us; speedup vs baseline: 1.4275x; 1.0140x over previous
//
#include <hip/hip_runtime.h>

typedef _Float16 f16;
typedef _Float16 f16x4 __attribute__((ext_vector_type(4)));
typedef _Float16 n16x2 __attribute__((ext_vector_type(2)));
typedef float    f32x4 __attribute__((ext_vector_type(4)));

#define LOG2E 1.44269504088896340736f
#define OFF25 36.0673760222824936f   /* 25 * log2(e) */

__device__ __forceinline__ f32x4 MFMA(f16x4 a, f16x4 b, f32x4 c) {
#if defined(__HIP_DEVICE_COMPILE__)
    return __builtin_amdgcn_mfma_f32_16x16x16f16(a, b, c, 0, 0, 0);
#else
    return c;   // host parse stub — never executed
#endif
}

__device__ __forceinline__ float fexp2(float x) {
#if defined(__HIP_DEVICE_COMPILE__)
    return __builtin_amdgcn_exp2f(x);
#else
    return exp2f(x);
#endif
}

__device__ __forceinline__ float flog2(float x) {
#if defined(__HIP_DEVICE_COMPILE__)
    return __builtin_amdgcn_logf(x);     // v_log_f32 = log2
#else
    return log2f(x);
#endif
}

__device__ __forceinline__ f16x4 pk4(float a, float b, float c, float d) {
#if defined(__HIP_DEVICE_COMPILE__)
    n16x2 lo = __builtin_bit_cast(n16x2, __builtin_amdgcn_cvt_pkrtz(a, b));
    n16x2 hi = __builtin_bit_cast(n16x2, __builtin_amdgcn_cvt_pkrtz(c, d));
    f16x4 r; r[0] = lo[0]; r[1] = lo[1]; r[2] = hi[0]; r[3] = hi[1];
    return r;
#else
    f16x4 r; r[0] = (f16)a; r[1] = (f16)b; r[2] = (f16)c; r[3] = (f16)d;
    return r;
#endif
}

// ---------------------------------------------------------------------------
// K1: projections, K-split, with LDS-staged COALESCED x reads.
// Block = 32 rows; 256 threads load 32x128 f32 via consecutive float4
// (perfect coalescing), pad 132 (banks spread 4/row -> 2-way, free).
// F pre-scaled by log2(e); H written directly as fragment-order f16.
// ---------------------------------------------------------------------------
__global__ __launch_bounds__(256) void k_proj(const float* __restrict__ x,
        const float* __restrict__ wf, const float* __restrict__ wg,
        const float* __restrict__ wh, f16* __restrict__ F,
        f16* __restrict__ G, f16* __restrict__ Hf) {
    const int tid = threadIdx.x;
    const long rowbase = (long)blockIdx.x * 32;

    __shared__ float xls[32][132];                   // 16.9 KB
    #pragma unroll
    for (int k = 0; k < 4; ++k) {
        const int fi = tid + k * 256;                // float4 index 0..1023
        const int r  = fi >> 5;                      // row 0..31
        const int c4 = fi & 31;                      // float4 col
        float4 v = *(const float4*)(x + (rowbase + r) * 128 + c4 * 4);
        *(float4*)&xls[r][c4 * 4] = v;
    }

    const int lane = tid & 63;
    const int wid  = tid >> 6;
    const int tile = wid >> 1;
    const int kh   = wid & 1;
    const int g16  = lane >> 4;
    const int c16  = lane & 15;
    const long r0  = rowbase + tile * 16;

    f16x4 bw[3][4];
    const float* Ws[3] = { wf, wg, wh };
    #pragma unroll
    for (int w = 0; w < 3; ++w)
        #pragma unroll
        for (int kk = 0; kk < 4; ++kk) {
            const int kb = (kh * 4 + kk) * 16 + g16 * 4;
            bw[w][kk] = pk4(Ws[w][(kb + 0) * 16 + c16], Ws[w][(kb + 1) * 16 + c16],
                            Ws[w][(kb + 2) * 16 + c16], Ws[w][(kb + 3) * 16 + c16]);
        }
    __syncthreads();

    f32x4 af = {0,0,0,0}, ag = {0,0,0,0}, ah = {0,0,0,0};
    #pragma unroll
    for (int kk = 0; kk < 4; ++kk) {
        const int col = kh * 64 + kk * 16 + g16 * 4;
        const float* xr = &xls[tile * 16 + c16][col];
        f16x4 a = pk4(xr[0], xr[1], xr[2], xr[3]);
        af = MFMA(a, bw[0][kk], af);
        ag = MFMA(a, bw[1][kk], ag);
        ah = MFMA(a, bw[2][kk], ah);
    }

    __shared__ float red[2][64][13];
    if (kh == 1) {
        #pragma unroll
        for (int i = 0; i < 4; ++i) {
            red[tile][lane][i]     = af[i];
            red[tile][lane][4 + i] = ag[i];
            red[tile][lane][8 + i] = ah[i];
        }
    }
    __syncthreads();
    if (kh == 0) {
        #pragma unroll
        for (int i = 0; i < 4; ++i) {
            af[i] += red[tile][lane][i];
            ag[i] += red[tile][lane][4 + i];
            ah[i] += red[tile][lane][8 + i];
        }
        #pragma unroll
        for (int i = 0; i < 4; ++i) {
            const long row = r0 + g16 * 4 + i;
            F[row * 16 + c16] = (f16)(af[i] * LOG2E);   // exp2-domain F
            G[row * 16 + c16] = (f16)ag[i];
        }
        *(f16x4*)(Hf + (r0 >> 4) * 256 + lane * 4) =
            pk4(ah[0], ah[1], ah[2], ah[3]);
    }
}

// ---------------------------------------------------------------------------
// K2: column Z, XCD swizzle, register-lean dual n-stream (round-18, proven).
// ---------------------------------------------------------------------------
__global__ __launch_bounds__(512) void k_cs(const f16* __restrict__ F,
        const f16* __restrict__ G, float* __restrict__ nM2) {
    const int lane = threadIdx.x & 63;
    const int tp   = threadIdx.x >> 6;               // 0..7 n-partition
    const int b    = blockIdx.x & 7;                 // XCD swizzle: batch
    const int mb   = (blockIdx.x >> 3) * 64;         //              m-block
    const int g16  = lane >> 4, c16 = lane & 15;
    const long bb  = (long)b * 4096;

    f16x4 ga[4];
    #pragma unroll
    for (int j = 0; j < 4; ++j)
        ga[j] = *(const f16x4*)(G + (bb + mb + 16 * j + c16) * 16 + g16 * 4);

    const f16* Fb = F + (bb + tp * 512) * 16;
    float zs[4][4];
    #pragma unroll
    for (int j = 0; j < 4; ++j)
        #pragma unroll
        for (int i = 0; i < 4; ++i) zs[j][i] = 0.f;

    const f32x4 coff = {-OFF25, -OFF25, -OFF25, -OFF25};
    f16x4 fa0 = *(const f16x4*)(Fb + (0 * 16 + c16) * 16 + g16 * 4);
    f16x4 fb0 = *(const f16x4*)(Fb + (1 * 16 + c16) * 16 + g16 * 4);
    f16x4 fa1 = *(const f16x4*)(Fb + (2 * 16 + c16) * 16 + g16 * 4);
    f16x4 fb1 = *(const f16x4*)(Fb + (3 * 16 + c16) * 16 + g16 * 4);
    for (int t = 0; t < 16; ++t) {
        f16x4 fa2 = *(const f16x4*)(Fb + ((2 * t + 4) * 16 + c16) * 16 + g16 * 4);
        f16x4 fb2 = *(const f16x4*)(Fb + ((2 * t + 5) * 16 + c16) * 16 + g16 * 4);
        #pragma unroll
        for (int j = 0; j < 4; ++j) {
            f32x4 sa = MFMA(ga[j], fa0, coff);
            f32x4 sb = MFMA(ga[j], fb0, coff);
            #pragma unroll
            for (int i = 0; i < 4; ++i) {
                zs[j][i] += fexp2(sa[i]);
                zs[j][i] += fexp2(sb[i]);
            }
        }
        fa0 = fa1; fb0 = fb1; fa1 = fa2; fb1 = fb2;
    }
    #pragma unroll
    for (int d = 8; d >= 1; d >>= 1)
        #pragma unroll
        for (int j = 0; j < 4; ++j)
            #pragma unroll
            for (int i = 0; i < 4; ++i)
                zs[j][i] += __shfl_xor(zs[j][i], d);

    __shared__ float lz[8][64];
    if (c16 == 0) {
        #pragma unroll
        for (int j = 0; j < 4; ++j)
            #pragma unroll
            for (int i = 0; i < 4; ++i)
                lz[tp][16 * j + 4 * g16 + i] = zs[j][i];
    }
    __syncthreads();
    if (threadIdx.x < 64) {
        const int ml = threadIdx.x;
        float z = 0.f;
        #pragma unroll
        for (int p = 0; p < 8; ++p) z += lz[p][ml];
        nM2[bb + mb + ml] = -flog2(z) - OFF25;
    }
}

// ---------------------------------------------------------------------------
// K3: PV + fused output projection, XCD swizzle, dual m-stream (round-19,
// proven).  Separate yTa/yTb accumulators; 16 iters x 2 m-tiles.
// ---------------------------------------------------------------------------
__global__ __launch_bounds__(512) void k_pv(const f16* __restrict__ F,
        const f16* __restrict__ G, const f16* __restrict__ Hf,
        const float* __restrict__ nM2, const float* __restrict__ wv,
        const float* __restrict__ xin, const float* __restrict__ gamma,
        float* __restrict__ out) {
    const int lane = threadIdx.x & 63;
    const int tp   = threadIdx.x >> 6;               // 0..7 m-partition
    const int b    = blockIdx.x & 7;                 // XCD swizzle: batch
    const int n0   = (blockIdx.x >> 3) * 64;         //              n-block
    const int g16  = lane >> 4, c16 = lane & 15;
    const long bb  = (long)b * 4096;

    f16x4 fbv[4];
    #pragma unroll
    for (int j = 0; j < 4; ++j)
        fbv[j] = *(const f16x4*)(F + (bb + n0 + 16 * j + c16) * 16 + g16 * 4);

    // epilogue assignment: wave tp -> n-tile jo, col-half th
    const int jo = tp >> 1, th = tp & 1;
    const float gm = gamma[0];
    f16x4 wvf[4];
    #pragma unroll
    for (int t = 0; t < 4; ++t) {
        const int c0 = (4 * th + t) * 16;
        wvf[t] = pk4(wv[(g16 * 4 + 0) * 128 + c0 + c16] * gm,
                     wv[(g16 * 4 + 1) * 128 + c0 + c16] * gm,
                     wv[(g16 * 4 + 2) * 128 + c0 + c16] * gm,
                     wv[(g16 * 4 + 3) * 128 + c0 + c16] * gm);
    }

    const f16* Gp = G + bb * 16;
    const f16* Hp = Hf + bb * 16 + lane * 4;         // frag-order: +m*16
    const float* Np = nM2 + bb;
    const int mbase = tp * 512;

    f32x4 yTa[4] = {{0,0,0,0},{0,0,0,0},{0,0,0,0},{0,0,0,0}};
    f32x4 yTb[4] = {{0,0,0,0},{0,0,0,0},{0,0,0,0},{0,0,0,0}};
    f16x4 gaa0 = *(const f16x4*)(Gp + (mbase + c16) * 16 + g16 * 4);
    f16x4 haa0 = *(const f16x4*)(Hp + (long)mbase * 16);
    f32x4 nma0 = *(const f32x4*)(Np + mbase + g16 * 4);
    f16x4 gab0 = *(const f16x4*)(Gp + (mbase + 16 + c16) * 16 + g16 * 4);
    f16x4 hab0 = *(const f16x4*)(Hp + (long)(mbase + 16) * 16);
    f32x4 nmb0 = *(const f32x4*)(Np + mbase + 16 + g16 * 4);
    f16x4 gaa1 = *(const f16x4*)(Gp + (mbase + 32 + c16) * 16 + g16 * 4);
    f16x4 haa1 = *(const f16x4*)(Hp + (long)(mbase + 32) * 16);
    f32x4 nma1 = *(const f32x4*)(Np + mbase + 32 + g16 * 4);
    f16x4 gab1 = *(const f16x4*)(Gp + (mbase + 48 + c16) * 16 + g16 * 4);
    f16x4 hab1 = *(const f16x4*)(Hp + (long)(mbase + 48) * 16);
    f32x4 nmb1 = *(const f32x4*)(Np + mbase + 48 + g16 * 4);
    for (int t = 0; t < 16; ++t) {
        const int mp = mbase + t * 32 + 64;   // pair-prefetch; PAD covers tail
        f16x4 gaa2 = *(const f16x4*)(Gp + (mp + c16) * 16 + g16 * 4);
        f16x4 haa2 = *(const f16x4*)(Hp + (long)mp * 16);
        f32x4 nma2 = *(const f32x4*)(Np + mp + g16 * 4);
        f16x4 gab2 = *(const f16x4*)(Gp + (mp + 16 + c16) * 16 + g16 * 4);
        f16x4 hab2 = *(const f16x4*)(Hp + (long)(mp + 16) * 16);
        f32x4 nmb2 = *(const f32x4*)(Np + mp + 16 + g16 * 4);
        #pragma unroll
        for (int j = 0; j < 4; ++j) {
            f32x4 sa = MFMA(gaa0, fbv[j], nma0);
            f16x4 pa = pk4(fexp2(sa[0]), fexp2(sa[1]),
                           fexp2(sa[2]), fexp2(sa[3]));
            yTa[j] = MFMA(haa0, pa, yTa[j]);
            f32x4 sb = MFMA(gab0, fbv[j], nmb0);
            f16x4 pb = pk4(fexp2(sb[0]), fexp2(sb[1]),
                           fexp2(sb[2]), fexp2(sb[3]));
            yTb[j] = MFMA(hab0, pb, yTb[j]);
        }
        gaa0 = gaa1; haa0 = haa1; nma0 = nma1;
        gab0 = gab1; hab0 = hab1; nmb0 = nmb1;
        gaa1 = gaa2; haa1 = haa2; nma1 = nma2;
        gab1 = gab2; hab1 = hab2; nmb1 = nmb2;
    }

    // cross-wave reduce: 8 m-partials per n-tile
    __shared__ float red[8][4][64][5];        // 40 KB, stride-5: conflict-free
    #pragma unroll
    for (int j = 0; j < 4; ++j)
        #pragma unroll
        for (int i = 0; i < 4; ++i) red[tp][j][lane][i] = yTa[j][i] + yTb[j][i];
    __syncthreads();

    f32x4 ys = {0,0,0,0};
    #pragma unroll
    for (int p = 0; p < 8; ++p)
        #pragma unroll
        for (int i = 0; i < 4; ++i) ys[i] += red[p][jo][lane][i];
    const f16x4 ya = pk4(ys[0], ys[1], ys[2], ys[3]);   // Y A-frag, n-tile jo

    #pragma unroll
    for (int t = 0; t < 4; ++t) {
        const int c0 = (4 * th + t) * 16;
        f32x4 zero = {0,0,0,0};
        f32x4 o = MFMA(ya, wvf[t], zero);
        #pragma unroll
        for (int i = 0; i < 4; ++i) {
            const long idx = (bb + n0 + 16 * jo + 4 * g16 + i) * 128 + c0 + c16;
            out[idx] = o[i] + xin[idx];
        }
    }
}

// ---------------------------------------------------------------------------
extern "C" void kernel_launch(void* const* d_in, const int* in_sizes, int n_in,
                              void* d_out, int out_size, void* d_ws, size_t ws_size,
                              hipStream_t stream) {
    const float* x     = (const float*)d_in[0];
    const float* wf    = (const float*)d_in[1];
    const float* wg    = (const float*)d_in[2];
    const float* wh    = (const float*)d_in[3];
    const float* wv    = (const float*)d_in[4];
    const float* gamma = (const float*)d_in[5];
    float* out = (float*)d_out;

    char* p = (char*)d_ws;
    const long BN  = 8L * 4096;
    const long PAD = 8192;
    f16*   F   = (f16*)p;    p += BN * 16 * sizeof(f16) + PAD;
    f16*   G   = (f16*)p;    p += BN * 16 * sizeof(f16) + PAD;
    f16*   Hf  = (f16*)p;    p += BN * 16 * sizeof(f16) + PAD;  // frag-order V
    float* nM2 = (float*)p;  p += BN * sizeof(float)    + PAD;

    k_proj<<<1024, 256, 0, stream>>>(x, wf, wg, wh, F, G, Hf);
    k_cs  <<<512,  512, 0, stream>>>(F, G, nM2);
    k_pv  <<<512,  512, 0, stream>>>(F, G, Hf, nM2, wv, x, gamma, out);
}